// Round 21
// baseline (74.766 us; speedup 1.0000x reference)
//
#include <hip/hip_runtime.h>
#include <hip/hip_bf16.h>
#include <math.h>

#define BSZ 4
#define NN 512
#define DD 64
#define NKEEP 256

typedef __attribute__((ext_vector_type(8))) short short8;
typedef __attribute__((ext_vector_type(4))) float f32x4;

__device__ __forceinline__ ushort f2bf_rne(float f) {
  union { float f; unsigned u; } v; v.f = f;
  unsigned r = v.u + 0x7fffu + ((v.u >> 16) & 1u);
  return (ushort)(r >> 16);
}
__device__ __forceinline__ float bf2f(ushort h) {
  union { unsigned u; float f; } v; v.u = ((unsigned)h) << 16;
  return v.f;
}
__device__ __forceinline__ void split2t(float a, float b, uint& hu, uint& lu) {
  const uint au = __float_as_uint(a), bu = __float_as_uint(b);
  hu = (au >> 16) | (bu & 0xffff0000u);
  const float ra = a - __uint_as_float(au & 0xffff0000u);  // exact
  const float rb = b - __uint_as_float(bu & 0xffff0000u);  // exact
  lu = (__float_as_uint(ra) >> 16) | (__float_as_uint(rb) & 0xffff0000u);
}

// ============ Kernel A: PERSISTENT symmetric scores, balanced + small body ===
// 528 blocks x 4 waves = 2112 waves; EXACTLY 2 tasks each (was 2048 waves with
// a 128-wave 3-task tail -> duration was 3 task-times).  ii loop unroll-2 with
// named 2-deep prefetch: body ~3KB fits I-cache (full unroll was ~12KB+).
__global__ __launch_bounds__(256, 1) void k_score(
    const float* __restrict__ x, const float* __restrict__ apw,
    const float* __restrict__ apb, const float* __restrict__ aw,
    float* __restrict__ sT) {
  __shared__ __align__(16) float T[4][8][16];  // per-wave mirror tiles

  const int w = threadIdx.x >> 6;
  const int l = threadIdx.x & 63;
  const int il = l & 15, g = l >> 4;

  short8 wfh[4][2], wfl[4][2];
  #pragma unroll
  for (int eq = 0; eq < 4; ++eq)
    #pragma unroll
    for (int ks = 0; ks < 2; ++ks) {
      short8 hh, ll;
      #pragma unroll
      for (int q = 0; q < 8; ++q) {
        const int d = ks * 32 + g * 8 + q;
        const float wv = apw[d * 64 + eq * 16 + il];
        const ushort h = f2bf_rne(wv);
        hh[q] = (short)h;
        ll[q] = (short)f2bf_rne(wv - bf2f(h));
      }
      wfh[eq][ks] = hh; wfl[eq][ks] = ll;
    }

  const float K2 = 2.8853900817779268f;  // 2/ln2
  float aw2_4[4], bK2[4], awq = 0.f;
  #pragma unroll
  for (int eq = 0; eq < 4; ++eq) {
    const float a = aw[eq * 16 + il];
    aw2_4[eq] = 2.f * a;
    bK2[eq] = apb[eq * 16 + il] * K2;
    awq += a;
  }
  awq += __shfl_xor(awq, 1, 64);
  awq += __shfl_xor(awq, 2, 64);
  awq += __shfl_xor(awq, 4, 64);
  awq += __shfl_xor(awq, 8, 64);
  const float awC = awq;

  const int wave_id = blockIdx.x * 4 + w;  // 0..2111

  #pragma unroll 1
  for (int tsel = 0; tsel < 2; ++tsel) {
    const int task = wave_id + tsel * 2112;  // exactly 2 tasks per wave
    const int b = task / 1056;
    const int pid = task - b * 1056;
    int it = 0, rem = pid;
    while (rem >= 32 - (it >> 1)) { rem -= 32 - (it >> 1); ++it; }
    const int jt = (it >> 1) + rem;
    const int i0 = it * 8, j0 = jt * 16;
    const bool diag = ((it >> 1) == jt);

    const float* xb = x + (size_t)b * NN * DD;
    float* plane = sT + (size_t)b * NN * NN;

    const float* xjr = xb + (size_t)(j0 + il) * DD;
    const float4 xj0 = *reinterpret_cast<const float4*>(xjr + g * 8);
    const float4 xj1 = *reinterpret_cast<const float4*>(xjr + g * 8 + 4);
    const float4 xj2 = *reinterpret_cast<const float4*>(xjr + 32 + g * 8);
    const float4 xj3 = *reinterpret_cast<const float4*>(xjr + 32 + g * 8 + 4);

    // 2-deep named prefetch buffers (static indexing under unroll-2)
    float4 pfA[4], pfB[4];
    {
      const float* xir = xb + (size_t)i0 * DD;
      pfA[0] = *reinterpret_cast<const float4*>(xir + g * 8);
      pfA[1] = *reinterpret_cast<const float4*>(xir + g * 8 + 4);
      pfA[2] = *reinterpret_cast<const float4*>(xir + 32 + g * 8);
      pfA[3] = *reinterpret_cast<const float4*>(xir + 32 + g * 8 + 4);
    }

    #pragma unroll 2
    for (int ii = 0; ii < 8; ++ii) {
      const int i_glob = i0 + ii;
      float4* cur = (ii & 1) ? pfB : pfA;
      float4* nxt = (ii & 1) ? pfA : pfB;
      if (ii < 7) {  // prefetch next row into the other buffer
        const float* xir = xb + (size_t)(i_glob + 1) * DD;
        nxt[0] = *reinterpret_cast<const float4*>(xir + g * 8);
        nxt[1] = *reinterpret_cast<const float4*>(xir + g * 8 + 4);
        nxt[2] = *reinterpret_cast<const float4*>(xir + 32 + g * 8);
        nxt[3] = *reinterpret_cast<const float4*>(xir + 32 + g * 8 + 4);
      }
      const float4 xi0 = cur[0], xi1 = cur[1], xi2 = cur[2], xi3 = cur[3];

      union { uint u[4]; short8 s; } hA, lA, hB, lB;
      split2t(xj0.x * xi0.x, xj0.y * xi0.y, hA.u[0], lA.u[0]);
      split2t(xj0.z * xi0.z, xj0.w * xi0.w, hA.u[1], lA.u[1]);
      split2t(xj1.x * xi1.x, xj1.y * xi1.y, hA.u[2], lA.u[2]);
      split2t(xj1.z * xi1.z, xj1.w * xi1.w, hA.u[3], lA.u[3]);
      split2t(xj2.x * xi2.x, xj2.y * xi2.y, hB.u[0], lB.u[0]);
      split2t(xj2.z * xi2.z, xj2.w * xi2.w, hB.u[1], lB.u[1]);
      split2t(xj3.x * xi3.x, xj3.y * xi3.y, hB.u[2], lB.u[2]);
      split2t(xj3.z * xi3.z, xj3.w * xi3.w, hB.u[3], lB.u[3]);

      f32x4 acc[4];
      #pragma unroll
      for (int eq = 0; eq < 4; ++eq) acc[eq] = (f32x4){0.f, 0.f, 0.f, 0.f};
      #pragma unroll
      for (int eq = 0; eq < 4; ++eq) {
        acc[eq] = __builtin_amdgcn_mfma_f32_16x16x32_bf16(hA.s, wfh[eq][0], acc[eq], 0, 0, 0);
        acc[eq] = __builtin_amdgcn_mfma_f32_16x16x32_bf16(hA.s, wfl[eq][0], acc[eq], 0, 0, 0);
        acc[eq] = __builtin_amdgcn_mfma_f32_16x16x32_bf16(lA.s, wfh[eq][0], acc[eq], 0, 0, 0);
        acc[eq] = __builtin_amdgcn_mfma_f32_16x16x32_bf16(hB.s, wfh[eq][1], acc[eq], 0, 0, 0);
        acc[eq] = __builtin_amdgcn_mfma_f32_16x16x32_bf16(hB.s, wfl[eq][1], acc[eq], 0, 0, 0);
        acc[eq] = __builtin_amdgcn_mfma_f32_16x16x32_bf16(lB.s, wfh[eq][1], acc[eq], 0, 0, 0);
      }

      float neg[4] = {0.f, 0.f, 0.f, 0.f};
      #pragma unroll
      for (int eq = 0; eq < 4; ++eq)
        #pragma unroll
        for (int rr = 0; rr < 4; ++rr) {
          const float ex = __builtin_amdgcn_exp2f(fmaf(acc[eq][rr], K2, bK2[eq]));
          const float rc = __builtin_amdgcn_rcpf(ex + 1.0f);
          neg[rr] = fmaf(aw2_4[eq], rc, neg[rr]);
        }
      #pragma unroll
      for (int rr = 0; rr < 4; ++rr) {
        neg[rr] += __shfl_xor(neg[rr], 1, 64);
        neg[rr] += __shfl_xor(neg[rr], 2, 64);
        neg[rr] += __shfl_xor(neg[rr], 4, 64);
        neg[rr] += __shfl_xor(neg[rr], 8, 64);
      }
      const f32x4 sc = {awC - neg[0], awC - neg[1], awC - neg[2], awC - neg[3]};

      if (il == 0) {
        if (!diag) {
          *reinterpret_cast<f32x4*>(plane + (size_t)i_glob * NN + j0 + g * 4) = sc;
        } else {
          #pragma unroll
          for (int rr = 0; rr < 4; ++rr) {
            const int jv = j0 + g * 4 + rr;
            if (jv >= i_glob) plane[(size_t)i_glob * NN + jv] = sc[rr];
          }
        }
        *reinterpret_cast<f32x4*>(&T[w][ii][g * 4]) = sc;
      }
    }

    {
      const int jv = l >> 2;
      const int ip = (l & 3) * 2;
      const float m0 = T[w][ip + 0][jv];
      const float m1 = T[w][ip + 1][jv];
      const int jr = j0 + jv;
      if (!diag) {
        const float2 mv = {m0, m1};
        *reinterpret_cast<float2*>(plane + (size_t)jr * NN + i0 + ip) = mv;
      } else {
        if (jr > i0 + ip + 0) plane[(size_t)jr * NN + i0 + ip + 0] = m0;
        if (jr > i0 + ip + 1) plane[(size_t)jr * NN + i0 + ip + 1] = m1;
      }
    }
  }
}

// ====== Kernel B: PERSISTENT softmax+agg+h+BN+SELU+s (unchanged) =============
__global__ __launch_bounds__(256, 1) void k_soft(
    const float* __restrict__ x, const float* __restrict__ sT,
    const float* __restrict__ pwa, const float* __restrict__ pwab,
    const float* __restrict__ pwoa, const float* __restrict__ pwob,
    const float* __restrict__ gam, const float* __restrict__ bet,
    const float* __restrict__ mu, const float* __restrict__ var,
    const float* __restrict__ poolw, const float* __restrict__ poolb,
    float* __restrict__ h, float* __restrict__ s) {
  __shared__ float ssc[2][512];
  __shared__ float srm[2][4], srs[2][4];
  __shared__ float sagg[4][2][64];
  __shared__ float rag[2][64], xis[2][64];

  const int t = threadIdx.x;
  const int w = t >> 6, l = t & 63;
  const int jw = w * 128;

  #pragma unroll 1
  for (int task = blockIdx.x; task < 1024; task += 512) {
    const int b = task >> 8;
    const int rp = task & 255;
    const int i_r0 = rp * 2, i_r1 = i_r0 + 1;
    const float* xb = x + (size_t)b * NN * DD;
    const float* pl0 = sT + (size_t)b * NN * NN;

    const size_t o0 = (size_t)i_r0 * NN + jw + l;
    const size_t o1 = (size_t)i_r1 * NN + jw + l;
    float r0a = pl0[o0];
    float r0b = pl0[o0 + 64];
    float r1a = pl0[o1];
    float r1b = pl0[o1 + 64];
    float m0 = fmaxf(r0a, r0b), m1 = fmaxf(r1a, r1b);
    #pragma unroll
    for (int off = 32; off; off >>= 1) {
      m0 = fmaxf(m0, __shfl_xor(m0, off, 64));
      m1 = fmaxf(m1, __shfl_xor(m1, off, 64));
    }
    if (l == 0) { srm[0][w] = m0; srm[1][w] = m1; }
    __syncthreads();
    m0 = fmaxf(fmaxf(srm[0][0], srm[0][1]), fmaxf(srm[0][2], srm[0][3]));
    m1 = fmaxf(fmaxf(srm[1][0], srm[1][1]), fmaxf(srm[1][2], srm[1][3]));

    const float L2E = 1.4426950408889634f;
    float e0a = __builtin_amdgcn_exp2f((r0a - m0) * L2E);
    float e0b = __builtin_amdgcn_exp2f((r0b - m0) * L2E);
    float e1a = __builtin_amdgcn_exp2f((r1a - m1) * L2E);
    float e1b = __builtin_amdgcn_exp2f((r1b - m1) * L2E);
    float ps0 = e0a + e0b, ps1 = e1a + e1b;
    #pragma unroll
    for (int off = 32; off; off >>= 1) {
      ps0 += __shfl_xor(ps0, off, 64);
      ps1 += __shfl_xor(ps1, off, 64);
    }
    if (l == 0) { srs[0][w] = ps0; srs[1][w] = ps1; }
    __syncthreads();
    const float inv0 = 1.f / (srs[0][0] + srs[0][1] + srs[0][2] + srs[0][3]);
    const float inv1 = 1.f / (srs[1][0] + srs[1][1] + srs[1][2] + srs[1][3]);
    ssc[0][jw + l] = e0a * inv0;
    ssc[0][jw + 64 + l] = e0b * inv0;
    ssc[1][jw + l] = e1a * inv1;
    ssc[1][jw + 64 + l] = e1b * inv1;
    __syncthreads();

    float g0a = 0.f, g0b = 0.f, g1a = 0.f, g1b = 0.f;
    #pragma unroll 4
    for (int jj = 0; jj < 128; jj += 2) {
      const int j = jw + jj;
      const float xv0 = xb[(size_t)j * DD + l];
      const float xv1 = xb[(size_t)(j + 1) * DD + l];
      g0a = fmaf(ssc[0][j], xv0, g0a);
      g1a = fmaf(ssc[1][j], xv0, g1a);
      g0b = fmaf(ssc[0][j + 1], xv1, g0b);
      g1b = fmaf(ssc[1][j + 1], xv1, g1b);
    }
    sagg[w][0][l] = g0a + g0b;
    sagg[w][1][l] = g1a + g1b;
    __syncthreads();

    if (w < 2) {
      const int irow = i_r0 + w;
      rag[w][l] = sagg[0][w][l] + sagg[1][w][l] + sagg[2][w][l] + sagg[3][w][l];
      xis[w][l] = xb[(size_t)irow * DD + l];
      float acc = 0.f;
      #pragma unroll 8
      for (int d = 0; d < 64; ++d) {
        acc = fmaf(rag[w][d], pwa[d * 64 + l], acc);
        acc = fmaf(xis[w][d], pwoa[d * 64 + l], acc);
      }
      acc += pwab[l] + pwob[l];
      float hb = (acc - mu[l]) * rsqrtf(var[l] + 1e-5f) * gam[l] + bet[l];
      const float SC = 1.0507009873554805f, AL = 1.6732632423543772f;
      float hv = hb > 0.f ? SC * hb : SC * AL * expm1f(hb);
      h[((size_t)(b * NN + irow)) * DD + l] = hv;

      float p = hv * poolw[l];
      #pragma unroll
      for (int off = 32; off; off >>= 1) p += __shfl_xor(p, off, 64);
      if (l == 0) s[b * NN + irow] = 1.f / (1.f + expf(-(p + poolb[0])));
    }
    __syncthreads();  // protect rag/xis/sagg before next iteration reuses LDS
  }
}

// ====== Kernel C: fused per-batch rank-select top-k + gather =================
__global__ __launch_bounds__(512) void k_sel(
    const float* __restrict__ s, const float* __restrict__ h,
    float* __restrict__ out) {
  __shared__ float svv[NN];
  __shared__ int inv[NKEEP];
  __shared__ float sval[NKEEP];
  const int b = blockIdx.x, t = threadIdx.x;
  svv[t] = s[b * NN + t];
  __syncthreads();

  const float my = svv[t];
  int r = 0;
  #pragma unroll 4
  for (int j0 = 0; j0 < NN; j0 += 4) {
    float4 v = *reinterpret_cast<const float4*>(&svv[j0]);
    r += (v.x > my) || (v.x == my && (j0 + 0) < t);
    r += (v.y > my) || (v.y == my && (j0 + 1) < t);
    r += (v.z > my) || (v.z == my && (j0 + 2) < t);
    r += (v.w > my) || (v.w == my && (j0 + 3) < t);
  }
  if (r < NKEEP) { inv[r] = t; sval[r] = my; }
  __syncthreads();

  #pragma unroll
  for (int pos = t; pos < NKEEP * 16; pos += 512) {
    const int kk = pos >> 4, d4 = (pos & 15) * 4;
    const int i = inv[kk];
    const float sc = sval[kk];
    float4 v = *reinterpret_cast<const float4*>(
        h + ((size_t)(b * NN + i)) * DD + d4);
    v.x *= sc; v.y *= sc; v.z *= sc; v.w *= sc;
    *reinterpret_cast<float4*>(out + ((size_t)(b * NKEEP + kk)) * DD + d4) = v;
  }
}

extern "C" void kernel_launch(void* const* d_in, const int* in_sizes, int n_in,
                              void* d_out, int out_size, void* d_ws, size_t ws_size,
                              hipStream_t stream) {
  const float* x     = (const float*)d_in[0];
  const float* apw   = (const float*)d_in[1];
  const float* apb   = (const float*)d_in[2];
  const float* aw    = (const float*)d_in[3];
  const float* pwa   = (const float*)d_in[4];
  const float* pwab  = (const float*)d_in[5];
  const float* pwoa  = (const float*)d_in[6];
  const float* pwob  = (const float*)d_in[7];
  const float* gam   = (const float*)d_in[8];
  const float* bet   = (const float*)d_in[9];
  const float* mu    = (const float*)d_in[10];
  const float* var   = (const float*)d_in[11];
  const float* poolw = (const float*)d_in[12];
  const float* poolb = (const float*)d_in[13];
  float* out = (float*)d_out;

  float* sT = (float*)d_ws;                     // 4 MB
  float* h  = sT + (size_t)BSZ * NN * NN;       // 512 KB
  float* s  = h + (size_t)BSZ * NN * DD;        // 8 KB

  k_score<<<528, 256, 0, stream>>>(x, apw, apb, aw, sT);
  k_soft<<<512, 256, 0, stream>>>(x, sT, pwa, pwab, pwoa, pwob,
                                  gam, bet, mu, var, poolw, poolb, h, s);
  k_sel<<<BSZ, 512, 0, stream>>>(s, h, out);
}

// Round 22
// 73.707 us; speedup vs baseline: 1.0144x; 1.0144x over previous
//
#include <hip/hip_runtime.h>
#include <hip/hip_bf16.h>
#include <math.h>

#define BSZ 4
#define NN 512
#define DD 64
#define NKEEP 256

typedef __attribute__((ext_vector_type(8))) short short8;
typedef __attribute__((ext_vector_type(4))) float f32x4;

__device__ __forceinline__ ushort f2bf_rne(float f) {
  union { float f; unsigned u; } v; v.f = f;
  unsigned r = v.u + 0x7fffu + ((v.u >> 16) & 1u);
  return (ushort)(r >> 16);
}
__device__ __forceinline__ float bf2f(ushort h) {
  union { unsigned u; float f; } v; v.u = ((unsigned)h) << 16;
  return v.f;
}
__device__ __forceinline__ void split2t(float a, float b, uint& hu, uint& lu) {
  const uint au = __float_as_uint(a), bu = __float_as_uint(b);
  hu = (au >> 16) | (bu & 0xffff0000u);
  const float ra = a - __uint_as_float(au & 0xffff0000u);  // exact
  const float rb = b - __uint_as_float(bu & 0xffff0000u);  // exact
  lu = (__float_as_uint(ra) >> 16) | (__float_as_uint(rb) & 0xffff0000u);
}

// ============ Kernel A: PERSISTENT symmetric scores (R20 body, balanced) =====
// 528 blocks x 4 waves = 2112 waves; EXACTLY 2 tasks each.  Body identical to
// R20 (full unroll, 4-deep pf[4][4] prefetch, ii&3 constant under full unroll).
__global__ __launch_bounds__(256, 1) void k_score(
    const float* __restrict__ x, const float* __restrict__ apw,
    const float* __restrict__ apb, const float* __restrict__ aw,
    float* __restrict__ sT) {
  __shared__ __align__(16) float T[4][8][16];  // per-wave mirror tiles

  const int w = threadIdx.x >> 6;
  const int l = threadIdx.x & 63;
  const int il = l & 15, g = l >> 4;

  short8 wfh[4][2], wfl[4][2];
  #pragma unroll
  for (int eq = 0; eq < 4; ++eq)
    #pragma unroll
    for (int ks = 0; ks < 2; ++ks) {
      short8 hh, ll;
      #pragma unroll
      for (int q = 0; q < 8; ++q) {
        const int d = ks * 32 + g * 8 + q;
        const float wv = apw[d * 64 + eq * 16 + il];
        const ushort h = f2bf_rne(wv);
        hh[q] = (short)h;
        ll[q] = (short)f2bf_rne(wv - bf2f(h));
      }
      wfh[eq][ks] = hh; wfl[eq][ks] = ll;
    }

  const float K2 = 2.8853900817779268f;  // 2/ln2
  float aw2_4[4], bK2[4], awq = 0.f;
  #pragma unroll
  for (int eq = 0; eq < 4; ++eq) {
    const float a = aw[eq * 16 + il];
    aw2_4[eq] = 2.f * a;
    bK2[eq] = apb[eq * 16 + il] * K2;
    awq += a;
  }
  awq += __shfl_xor(awq, 1, 64);
  awq += __shfl_xor(awq, 2, 64);
  awq += __shfl_xor(awq, 4, 64);
  awq += __shfl_xor(awq, 8, 64);
  const float awC = awq;

  const int wave_id = blockIdx.x * 4 + w;  // 0..2111

  #pragma unroll 1
  for (int tsel = 0; tsel < 2; ++tsel) {
    const int task = wave_id + tsel * 2112;  // exactly 2 tasks per wave
    const int b = task / 1056;
    const int pid = task - b * 1056;
    int it = 0, rem = pid;
    while (rem >= 32 - (it >> 1)) { rem -= 32 - (it >> 1); ++it; }
    const int jt = (it >> 1) + rem;
    const int i0 = it * 8, j0 = jt * 16;
    const bool diag = ((it >> 1) == jt);

    const float* xb = x + (size_t)b * NN * DD;
    float* plane = sT + (size_t)b * NN * NN;

    // xj slices for the task (issued first)
    const float* xjr = xb + (size_t)(j0 + il) * DD;
    const float4 xj0 = *reinterpret_cast<const float4*>(xjr + g * 8);
    const float4 xj1 = *reinterpret_cast<const float4*>(xjr + g * 8 + 4);
    const float4 xj2 = *reinterpret_cast<const float4*>(xjr + 32 + g * 8);
    const float4 xj3 = *reinterpret_cast<const float4*>(xjr + 32 + g * 8 + 4);

    // ---- 4-deep rolling xi prefetch: preload rows 0..3 ----
    float4 pf[4][4];
    #pragma unroll
    for (int r = 0; r < 4; ++r) {
      const float* xir = xb + (size_t)(i0 + r) * DD;
      pf[r][0] = *reinterpret_cast<const float4*>(xir + g * 8);
      pf[r][1] = *reinterpret_cast<const float4*>(xir + g * 8 + 4);
      pf[r][2] = *reinterpret_cast<const float4*>(xir + 32 + g * 8);
      pf[r][3] = *reinterpret_cast<const float4*>(xir + 32 + g * 8 + 4);
    }

    #pragma unroll
    for (int ii = 0; ii < 8; ++ii) {
      const int i_glob = i0 + ii;
      const float4 xi0 = pf[ii & 3][0];
      const float4 xi1 = pf[ii & 3][1];
      const float4 xi2 = pf[ii & 3][2];
      const float4 xi3 = pf[ii & 3][3];
      if (ii < 4) {  // refill the consumed slot with row ii+4
        const float* xir = xb + (size_t)(i0 + ii + 4) * DD;
        pf[ii & 3][0] = *reinterpret_cast<const float4*>(xir + g * 8);
        pf[ii & 3][1] = *reinterpret_cast<const float4*>(xir + g * 8 + 4);
        pf[ii & 3][2] = *reinterpret_cast<const float4*>(xir + 32 + g * 8);
        pf[ii & 3][3] = *reinterpret_cast<const float4*>(xir + 32 + g * 8 + 4);
      }

      union { uint u[4]; short8 s; } hA, lA, hB, lB;
      split2t(xj0.x * xi0.x, xj0.y * xi0.y, hA.u[0], lA.u[0]);
      split2t(xj0.z * xi0.z, xj0.w * xi0.w, hA.u[1], lA.u[1]);
      split2t(xj1.x * xi1.x, xj1.y * xi1.y, hA.u[2], lA.u[2]);
      split2t(xj1.z * xi1.z, xj1.w * xi1.w, hA.u[3], lA.u[3]);
      split2t(xj2.x * xi2.x, xj2.y * xi2.y, hB.u[0], lB.u[0]);
      split2t(xj2.z * xi2.z, xj2.w * xi2.w, hB.u[1], lB.u[1]);
      split2t(xj3.x * xi3.x, xj3.y * xi3.y, hB.u[2], lB.u[2]);
      split2t(xj3.z * xi3.z, xj3.w * xi3.w, hB.u[3], lB.u[3]);

      f32x4 acc[4];
      #pragma unroll
      for (int eq = 0; eq < 4; ++eq) acc[eq] = (f32x4){0.f, 0.f, 0.f, 0.f};
      #pragma unroll
      for (int eq = 0; eq < 4; ++eq) {
        acc[eq] = __builtin_amdgcn_mfma_f32_16x16x32_bf16(hA.s, wfh[eq][0], acc[eq], 0, 0, 0);
        acc[eq] = __builtin_amdgcn_mfma_f32_16x16x32_bf16(hA.s, wfl[eq][0], acc[eq], 0, 0, 0);
        acc[eq] = __builtin_amdgcn_mfma_f32_16x16x32_bf16(lA.s, wfh[eq][0], acc[eq], 0, 0, 0);
        acc[eq] = __builtin_amdgcn_mfma_f32_16x16x32_bf16(hB.s, wfh[eq][1], acc[eq], 0, 0, 0);
        acc[eq] = __builtin_amdgcn_mfma_f32_16x16x32_bf16(hB.s, wfl[eq][1], acc[eq], 0, 0, 0);
        acc[eq] = __builtin_amdgcn_mfma_f32_16x16x32_bf16(lB.s, wfh[eq][1], acc[eq], 0, 0, 0);
      }

      float neg[4] = {0.f, 0.f, 0.f, 0.f};
      #pragma unroll
      for (int eq = 0; eq < 4; ++eq)
        #pragma unroll
        for (int rr = 0; rr < 4; ++rr) {
          const float ex = __builtin_amdgcn_exp2f(fmaf(acc[eq][rr], K2, bK2[eq]));
          const float rc = __builtin_amdgcn_rcpf(ex + 1.0f);
          neg[rr] = fmaf(aw2_4[eq], rc, neg[rr]);
        }
      #pragma unroll
      for (int rr = 0; rr < 4; ++rr) {
        neg[rr] += __shfl_xor(neg[rr], 1, 64);
        neg[rr] += __shfl_xor(neg[rr], 2, 64);
        neg[rr] += __shfl_xor(neg[rr], 4, 64);
        neg[rr] += __shfl_xor(neg[rr], 8, 64);
      }
      const f32x4 sc = {awC - neg[0], awC - neg[1], awC - neg[2], awC - neg[3]};

      if (il == 0) {
        if (!diag) {
          *reinterpret_cast<f32x4*>(plane + (size_t)i_glob * NN + j0 + g * 4) = sc;
        } else {
          #pragma unroll
          for (int rr = 0; rr < 4; ++rr) {
            const int jv = j0 + g * 4 + rr;
            if (jv >= i_glob) plane[(size_t)i_glob * NN + jv] = sc[rr];
          }
        }
        *reinterpret_cast<f32x4*>(&T[w][ii][g * 4]) = sc;
      }
    }

    {
      const int jv = l >> 2;
      const int ip = (l & 3) * 2;
      const float m0 = T[w][ip + 0][jv];
      const float m1 = T[w][ip + 1][jv];
      const int jr = j0 + jv;
      if (!diag) {
        const float2 mv = {m0, m1};
        *reinterpret_cast<float2*>(plane + (size_t)jr * NN + i0 + ip) = mv;
      } else {
        if (jr > i0 + ip + 0) plane[(size_t)jr * NN + i0 + ip + 0] = m0;
        if (jr > i0 + ip + 1) plane[(size_t)jr * NN + i0 + ip + 1] = m1;
      }
    }
  }
}

// ====== Kernel B: PERSISTENT softmax+agg+h+BN+SELU+s (unchanged) =============
__global__ __launch_bounds__(256, 1) void k_soft(
    const float* __restrict__ x, const float* __restrict__ sT,
    const float* __restrict__ pwa, const float* __restrict__ pwab,
    const float* __restrict__ pwoa, const float* __restrict__ pwob,
    const float* __restrict__ gam, const float* __restrict__ bet,
    const float* __restrict__ mu, const float* __restrict__ var,
    const float* __restrict__ poolw, const float* __restrict__ poolb,
    float* __restrict__ h, float* __restrict__ s) {
  __shared__ float ssc[2][512];
  __shared__ float srm[2][4], srs[2][4];
  __shared__ float sagg[4][2][64];
  __shared__ float rag[2][64], xis[2][64];

  const int t = threadIdx.x;
  const int w = t >> 6, l = t & 63;
  const int jw = w * 128;

  #pragma unroll 1
  for (int task = blockIdx.x; task < 1024; task += 512) {
    const int b = task >> 8;
    const int rp = task & 255;
    const int i_r0 = rp * 2, i_r1 = i_r0 + 1;
    const float* xb = x + (size_t)b * NN * DD;
    const float* pl0 = sT + (size_t)b * NN * NN;

    const size_t o0 = (size_t)i_r0 * NN + jw + l;
    const size_t o1 = (size_t)i_r1 * NN + jw + l;
    float r0a = pl0[o0];
    float r0b = pl0[o0 + 64];
    float r1a = pl0[o1];
    float r1b = pl0[o1 + 64];
    float m0 = fmaxf(r0a, r0b), m1 = fmaxf(r1a, r1b);
    #pragma unroll
    for (int off = 32; off; off >>= 1) {
      m0 = fmaxf(m0, __shfl_xor(m0, off, 64));
      m1 = fmaxf(m1, __shfl_xor(m1, off, 64));
    }
    if (l == 0) { srm[0][w] = m0; srm[1][w] = m1; }
    __syncthreads();
    m0 = fmaxf(fmaxf(srm[0][0], srm[0][1]), fmaxf(srm[0][2], srm[0][3]));
    m1 = fmaxf(fmaxf(srm[1][0], srm[1][1]), fmaxf(srm[1][2], srm[1][3]));

    const float L2E = 1.4426950408889634f;
    float e0a = __builtin_amdgcn_exp2f((r0a - m0) * L2E);
    float e0b = __builtin_amdgcn_exp2f((r0b - m0) * L2E);
    float e1a = __builtin_amdgcn_exp2f((r1a - m1) * L2E);
    float e1b = __builtin_amdgcn_exp2f((r1b - m1) * L2E);
    float ps0 = e0a + e0b, ps1 = e1a + e1b;
    #pragma unroll
    for (int off = 32; off; off >>= 1) {
      ps0 += __shfl_xor(ps0, off, 64);
      ps1 += __shfl_xor(ps1, off, 64);
    }
    if (l == 0) { srs[0][w] = ps0; srs[1][w] = ps1; }
    __syncthreads();
    const float inv0 = 1.f / (srs[0][0] + srs[0][1] + srs[0][2] + srs[0][3]);
    const float inv1 = 1.f / (srs[1][0] + srs[1][1] + srs[1][2] + srs[1][3]);
    ssc[0][jw + l] = e0a * inv0;
    ssc[0][jw + 64 + l] = e0b * inv0;
    ssc[1][jw + l] = e1a * inv1;
    ssc[1][jw + 64 + l] = e1b * inv1;
    __syncthreads();

    float g0a = 0.f, g0b = 0.f, g1a = 0.f, g1b = 0.f;
    #pragma unroll 4
    for (int jj = 0; jj < 128; jj += 2) {
      const int j = jw + jj;
      const float xv0 = xb[(size_t)j * DD + l];
      const float xv1 = xb[(size_t)(j + 1) * DD + l];
      g0a = fmaf(ssc[0][j], xv0, g0a);
      g1a = fmaf(ssc[1][j], xv0, g1a);
      g0b = fmaf(ssc[0][j + 1], xv1, g0b);
      g1b = fmaf(ssc[1][j + 1], xv1, g1b);
    }
    sagg[w][0][l] = g0a + g0b;
    sagg[w][1][l] = g1a + g1b;
    __syncthreads();

    if (w < 2) {
      const int irow = i_r0 + w;
      rag[w][l] = sagg[0][w][l] + sagg[1][w][l] + sagg[2][w][l] + sagg[3][w][l];
      xis[w][l] = xb[(size_t)irow * DD + l];
      float acc = 0.f;
      #pragma unroll 8
      for (int d = 0; d < 64; ++d) {
        acc = fmaf(rag[w][d], pwa[d * 64 + l], acc);
        acc = fmaf(xis[w][d], pwoa[d * 64 + l], acc);
      }
      acc += pwab[l] + pwob[l];
      float hb = (acc - mu[l]) * rsqrtf(var[l] + 1e-5f) * gam[l] + bet[l];
      const float SC = 1.0507009873554805f, AL = 1.6732632423543772f;
      float hv = hb > 0.f ? SC * hb : SC * AL * expm1f(hb);
      h[((size_t)(b * NN + irow)) * DD + l] = hv;

      float p = hv * poolw[l];
      #pragma unroll
      for (int off = 32; off; off >>= 1) p += __shfl_xor(p, off, 64);
      if (l == 0) s[b * NN + irow] = 1.f / (1.f + expf(-(p + poolb[0])));
    }
    __syncthreads();  // protect rag/xis/sagg before next iteration reuses LDS
  }
}

// ====== Kernel C: fused per-batch rank-select top-k + gather =================
__global__ __launch_bounds__(512) void k_sel(
    const float* __restrict__ s, const float* __restrict__ h,
    float* __restrict__ out) {
  __shared__ float svv[NN];
  __shared__ int inv[NKEEP];
  __shared__ float sval[NKEEP];
  const int b = blockIdx.x, t = threadIdx.x;
  svv[t] = s[b * NN + t];
  __syncthreads();

  const float my = svv[t];
  int r = 0;
  #pragma unroll 4
  for (int j0 = 0; j0 < NN; j0 += 4) {
    float4 v = *reinterpret_cast<const float4*>(&svv[j0]);
    r += (v.x > my) || (v.x == my && (j0 + 0) < t);
    r += (v.y > my) || (v.y == my && (j0 + 1) < t);
    r += (v.z > my) || (v.z == my && (j0 + 2) < t);
    r += (v.w > my) || (v.w == my && (j0 + 3) < t);
  }
  if (r < NKEEP) { inv[r] = t; sval[r] = my; }
  __syncthreads();

  #pragma unroll
  for (int pos = t; pos < NKEEP * 16; pos += 512) {
    const int kk = pos >> 4, d4 = (pos & 15) * 4;
    const int i = inv[kk];
    const float sc = sval[kk];
    float4 v = *reinterpret_cast<const float4*>(
        h + ((size_t)(b * NN + i)) * DD + d4);
    v.x *= sc; v.y *= sc; v.z *= sc; v.w *= sc;
    *reinterpret_cast<float4*>(out + ((size_t)(b * NKEEP + kk)) * DD + d4) = v;
  }
}

extern "C" void kernel_launch(void* const* d_in, const int* in_sizes, int n_in,
                              void* d_out, int out_size, void* d_ws, size_t ws_size,
                              hipStream_t stream) {
  const float* x     = (const float*)d_in[0];
  const float* apw   = (const float*)d_in[1];
  const float* apb   = (const float*)d_in[2];
  const float* aw    = (const float*)d_in[3];
  const float* pwa   = (const float*)d_in[4];
  const float* pwab  = (const float*)d_in[5];
  const float* pwoa  = (const float*)d_in[6];
  const float* pwob  = (const float*)d_in[7];
  const float* gam   = (const float*)d_in[8];
  const float* bet   = (const float*)d_in[9];
  const float* mu    = (const float*)d_in[10];
  const float* var   = (const float*)d_in[11];
  const float* poolw = (const float*)d_in[12];
  const float* poolb = (const float*)d_in[13];
  float* out = (float*)d_out;

  float* sT = (float*)d_ws;                     // 4 MB
  float* h  = sT + (size_t)BSZ * NN * NN;       // 512 KB
  float* s  = h + (size_t)BSZ * NN * DD;        // 8 KB

  k_score<<<528, 256, 0, stream>>>(x, apw, apb, aw, sT);
  k_soft<<<512, 256, 0, stream>>>(x, sT, pwa, pwab, pwoa, pwob,
                                  gam, bet, mu, var, poolw, poolb, h, s);
  k_sel<<<BSZ, 512, 0, stream>>>(s, h, out);
}

// Round 23
// 64.529 us; speedup vs baseline: 1.1586x; 1.1422x over previous
//
#include <hip/hip_runtime.h>
#include <hip/hip_bf16.h>
#include <math.h>

#define BSZ 4
#define NN 512
#define DD 64
#define NKEEP 256

typedef __attribute__((ext_vector_type(8))) short short8;
typedef __attribute__((ext_vector_type(4))) float f32x4;

__device__ __forceinline__ ushort f2bf_rne(float f) {
  union { float f; unsigned u; } v; v.f = f;
  unsigned r = v.u + 0x7fffu + ((v.u >> 16) & 1u);
  return (ushort)(r >> 16);
}
__device__ __forceinline__ float bf2f(ushort h) {
  union { unsigned u; float f; } v; v.u = ((unsigned)h) << 16;
  return v.f;
}
__device__ __forceinline__ void split2t(float a, float b, uint& hu, uint& lu) {
  const uint au = __float_as_uint(a), bu = __float_as_uint(b);
  hu = (au >> 16) | (bu & 0xffff0000u);
  const float ra = a - __uint_as_float(au & 0xffff0000u);  // exact
  const float rb = b - __uint_as_float(bu & 0xffff0000u);  // exact
  lu = (__float_as_uint(ra) >> 16) | (__float_as_uint(rb) & 0xffff0000u);
}

// ============ Kernel A: PERSISTENT symmetric scores + deep xi prefetch =======
// 512x256 persistent; wave grid-strides 4224 tasks (8i x 16j x 64e, jt>=it/2).
// xi rows prefetched 4-deep into registers (load-to-use ~4 iters >> L2 latency)
// so the per-row load stall (~400cy x 8, the measured 16K/task) is hidden.
__global__ __launch_bounds__(256, 1) void k_score(
    const float* __restrict__ x, const float* __restrict__ apw,
    const float* __restrict__ apb, const float* __restrict__ aw,
    float* __restrict__ sT) {
  __shared__ __align__(16) float T[4][8][16];  // per-wave mirror tiles

  const int w = threadIdx.x >> 6;
  const int l = threadIdx.x & 63;
  const int il = l & 15, g = l >> 4;

  short8 wfh[4][2], wfl[4][2];
  #pragma unroll
  for (int eq = 0; eq < 4; ++eq)
    #pragma unroll
    for (int ks = 0; ks < 2; ++ks) {
      short8 hh, ll;
      #pragma unroll
      for (int q = 0; q < 8; ++q) {
        const int d = ks * 32 + g * 8 + q;
        const float wv = apw[d * 64 + eq * 16 + il];
        const ushort h = f2bf_rne(wv);
        hh[q] = (short)h;
        ll[q] = (short)f2bf_rne(wv - bf2f(h));
      }
      wfh[eq][ks] = hh; wfl[eq][ks] = ll;
    }

  const float K2 = 2.8853900817779268f;  // 2/ln2
  float aw2_4[4], bK2[4], awq = 0.f;
  #pragma unroll
  for (int eq = 0; eq < 4; ++eq) {
    const float a = aw[eq * 16 + il];
    aw2_4[eq] = 2.f * a;
    bK2[eq] = apb[eq * 16 + il] * K2;
    awq += a;
  }
  awq += __shfl_xor(awq, 1, 64);
  awq += __shfl_xor(awq, 2, 64);
  awq += __shfl_xor(awq, 4, 64);
  awq += __shfl_xor(awq, 8, 64);
  const float awC = awq;

  const int wave_id = blockIdx.x * 4 + w;  // 0..2047

  for (int task = wave_id; task < 4224; task += 2048) {
    const int b = task / 1056;
    const int pid = task - b * 1056;
    int it = 0, rem = pid;
    while (rem >= 32 - (it >> 1)) { rem -= 32 - (it >> 1); ++it; }
    const int jt = (it >> 1) + rem;
    const int i0 = it * 8, j0 = jt * 16;
    const bool diag = ((it >> 1) == jt);

    const float* xb = x + (size_t)b * NN * DD;
    float* plane = sT + (size_t)b * NN * NN;

    // xj slices for the task (issued first)
    const float* xjr = xb + (size_t)(j0 + il) * DD;
    const float4 xj0 = *reinterpret_cast<const float4*>(xjr + g * 8);
    const float4 xj1 = *reinterpret_cast<const float4*>(xjr + g * 8 + 4);
    const float4 xj2 = *reinterpret_cast<const float4*>(xjr + 32 + g * 8);
    const float4 xj3 = *reinterpret_cast<const float4*>(xjr + 32 + g * 8 + 4);

    // ---- 4-deep rolling xi prefetch: preload rows 0..3 ----
    float4 pf[4][4];
    #pragma unroll
    for (int r = 0; r < 4; ++r) {
      const float* xir = xb + (size_t)(i0 + r) * DD;
      pf[r][0] = *reinterpret_cast<const float4*>(xir + g * 8);
      pf[r][1] = *reinterpret_cast<const float4*>(xir + g * 8 + 4);
      pf[r][2] = *reinterpret_cast<const float4*>(xir + 32 + g * 8);
      pf[r][3] = *reinterpret_cast<const float4*>(xir + 32 + g * 8 + 4);
    }

    #pragma unroll
    for (int ii = 0; ii < 8; ++ii) {
      const int i_glob = i0 + ii;
      const float4 xi0 = pf[ii & 3][0];
      const float4 xi1 = pf[ii & 3][1];
      const float4 xi2 = pf[ii & 3][2];
      const float4 xi3 = pf[ii & 3][3];
      if (ii < 4) {  // refill the consumed slot with row ii+4
        const float* xir = xb + (size_t)(i0 + ii + 4) * DD;
        pf[ii & 3][0] = *reinterpret_cast<const float4*>(xir + g * 8);
        pf[ii & 3][1] = *reinterpret_cast<const float4*>(xir + g * 8 + 4);
        pf[ii & 3][2] = *reinterpret_cast<const float4*>(xir + 32 + g * 8);
        pf[ii & 3][3] = *reinterpret_cast<const float4*>(xir + 32 + g * 8 + 4);
      }

      union { uint u[4]; short8 s; } hA, lA, hB, lB;
      split2t(xj0.x * xi0.x, xj0.y * xi0.y, hA.u[0], lA.u[0]);
      split2t(xj0.z * xi0.z, xj0.w * xi0.w, hA.u[1], lA.u[1]);
      split2t(xj1.x * xi1.x, xj1.y * xi1.y, hA.u[2], lA.u[2]);
      split2t(xj1.z * xi1.z, xj1.w * xi1.w, hA.u[3], lA.u[3]);
      split2t(xj2.x * xi2.x, xj2.y * xi2.y, hB.u[0], lB.u[0]);
      split2t(xj2.z * xi2.z, xj2.w * xi2.w, hB.u[1], lB.u[1]);
      split2t(xj3.x * xi3.x, xj3.y * xi3.y, hB.u[2], lB.u[2]);
      split2t(xj3.z * xi3.z, xj3.w * xi3.w, hB.u[3], lB.u[3]);

      f32x4 acc[4];
      #pragma unroll
      for (int eq = 0; eq < 4; ++eq) acc[eq] = (f32x4){0.f, 0.f, 0.f, 0.f};
      #pragma unroll
      for (int eq = 0; eq < 4; ++eq) {
        acc[eq] = __builtin_amdgcn_mfma_f32_16x16x32_bf16(hA.s, wfh[eq][0], acc[eq], 0, 0, 0);
        acc[eq] = __builtin_amdgcn_mfma_f32_16x16x32_bf16(hA.s, wfl[eq][0], acc[eq], 0, 0, 0);
        acc[eq] = __builtin_amdgcn_mfma_f32_16x16x32_bf16(lA.s, wfh[eq][0], acc[eq], 0, 0, 0);
        acc[eq] = __builtin_amdgcn_mfma_f32_16x16x32_bf16(hB.s, wfh[eq][1], acc[eq], 0, 0, 0);
        acc[eq] = __builtin_amdgcn_mfma_f32_16x16x32_bf16(hB.s, wfl[eq][1], acc[eq], 0, 0, 0);
        acc[eq] = __builtin_amdgcn_mfma_f32_16x16x32_bf16(lB.s, wfh[eq][1], acc[eq], 0, 0, 0);
      }

      float neg[4] = {0.f, 0.f, 0.f, 0.f};
      #pragma unroll
      for (int eq = 0; eq < 4; ++eq)
        #pragma unroll
        for (int rr = 0; rr < 4; ++rr) {
          const float ex = __builtin_amdgcn_exp2f(fmaf(acc[eq][rr], K2, bK2[eq]));
          const float rc = __builtin_amdgcn_rcpf(ex + 1.0f);
          neg[rr] = fmaf(aw2_4[eq], rc, neg[rr]);
        }
      #pragma unroll
      for (int rr = 0; rr < 4; ++rr) {
        neg[rr] += __shfl_xor(neg[rr], 1, 64);
        neg[rr] += __shfl_xor(neg[rr], 2, 64);
        neg[rr] += __shfl_xor(neg[rr], 4, 64);
        neg[rr] += __shfl_xor(neg[rr], 8, 64);
      }
      const f32x4 sc = {awC - neg[0], awC - neg[1], awC - neg[2], awC - neg[3]};

      if (il == 0) {
        if (!diag) {
          *reinterpret_cast<f32x4*>(plane + (size_t)i_glob * NN + j0 + g * 4) = sc;
        } else {
          #pragma unroll
          for (int rr = 0; rr < 4; ++rr) {
            const int jv = j0 + g * 4 + rr;
            if (jv >= i_glob) plane[(size_t)i_glob * NN + jv] = sc[rr];
          }
        }
        *reinterpret_cast<f32x4*>(&T[w][ii][g * 4]) = sc;
      }
    }

    {
      const int jv = l >> 2;
      const int ip = (l & 3) * 2;
      const float m0 = T[w][ip + 0][jv];
      const float m1 = T[w][ip + 1][jv];
      const int jr = j0 + jv;
      if (!diag) {
        const float2 mv = {m0, m1};
        *reinterpret_cast<float2*>(plane + (size_t)jr * NN + i0 + ip) = mv;
      } else {
        if (jr > i0 + ip + 0) plane[(size_t)jr * NN + i0 + ip + 0] = m0;
        if (jr > i0 + ip + 1) plane[(size_t)jr * NN + i0 + ip + 1] = m1;
      }
    }
  }
}

// ====== Kernel B: PERSISTENT softmax+agg+h+BN+SELU+s (unchanged) =============
__global__ __launch_bounds__(256, 1) void k_soft(
    const float* __restrict__ x, const float* __restrict__ sT,
    const float* __restrict__ pwa, const float* __restrict__ pwab,
    const float* __restrict__ pwoa, const float* __restrict__ pwob,
    const float* __restrict__ gam, const float* __restrict__ bet,
    const float* __restrict__ mu, const float* __restrict__ var,
    const float* __restrict__ poolw, const float* __restrict__ poolb,
    float* __restrict__ h, float* __restrict__ s) {
  __shared__ float ssc[2][512];
  __shared__ float srm[2][4], srs[2][4];
  __shared__ float sagg[4][2][64];
  __shared__ float rag[2][64], xis[2][64];

  const int t = threadIdx.x;
  const int w = t >> 6, l = t & 63;
  const int jw = w * 128;

  #pragma unroll 1
  for (int task = blockIdx.x; task < 1024; task += 512) {
    const int b = task >> 8;
    const int rp = task & 255;
    const int i_r0 = rp * 2, i_r1 = i_r0 + 1;
    const float* xb = x + (size_t)b * NN * DD;
    const float* pl0 = sT + (size_t)b * NN * NN;

    const size_t o0 = (size_t)i_r0 * NN + jw + l;
    const size_t o1 = (size_t)i_r1 * NN + jw + l;
    float r0a = pl0[o0];
    float r0b = pl0[o0 + 64];
    float r1a = pl0[o1];
    float r1b = pl0[o1 + 64];
    float m0 = fmaxf(r0a, r0b), m1 = fmaxf(r1a, r1b);
    #pragma unroll
    for (int off = 32; off; off >>= 1) {
      m0 = fmaxf(m0, __shfl_xor(m0, off, 64));
      m1 = fmaxf(m1, __shfl_xor(m1, off, 64));
    }
    if (l == 0) { srm[0][w] = m0; srm[1][w] = m1; }
    __syncthreads();
    m0 = fmaxf(fmaxf(srm[0][0], srm[0][1]), fmaxf(srm[0][2], srm[0][3]));
    m1 = fmaxf(fmaxf(srm[1][0], srm[1][1]), fmaxf(srm[1][2], srm[1][3]));

    const float L2E = 1.4426950408889634f;
    float e0a = __builtin_amdgcn_exp2f((r0a - m0) * L2E);
    float e0b = __builtin_amdgcn_exp2f((r0b - m0) * L2E);
    float e1a = __builtin_amdgcn_exp2f((r1a - m1) * L2E);
    float e1b = __builtin_amdgcn_exp2f((r1b - m1) * L2E);
    float ps0 = e0a + e0b, ps1 = e1a + e1b;
    #pragma unroll
    for (int off = 32; off; off >>= 1) {
      ps0 += __shfl_xor(ps0, off, 64);
      ps1 += __shfl_xor(ps1, off, 64);
    }
    if (l == 0) { srs[0][w] = ps0; srs[1][w] = ps1; }
    __syncthreads();
    const float inv0 = 1.f / (srs[0][0] + srs[0][1] + srs[0][2] + srs[0][3]);
    const float inv1 = 1.f / (srs[1][0] + srs[1][1] + srs[1][2] + srs[1][3]);
    ssc[0][jw + l] = e0a * inv0;
    ssc[0][jw + 64 + l] = e0b * inv0;
    ssc[1][jw + l] = e1a * inv1;
    ssc[1][jw + 64 + l] = e1b * inv1;
    __syncthreads();

    float g0a = 0.f, g0b = 0.f, g1a = 0.f, g1b = 0.f;
    #pragma unroll 4
    for (int jj = 0; jj < 128; jj += 2) {
      const int j = jw + jj;
      const float xv0 = xb[(size_t)j * DD + l];
      const float xv1 = xb[(size_t)(j + 1) * DD + l];
      g0a = fmaf(ssc[0][j], xv0, g0a);
      g1a = fmaf(ssc[1][j], xv0, g1a);
      g0b = fmaf(ssc[0][j + 1], xv1, g0b);
      g1b = fmaf(ssc[1][j + 1], xv1, g1b);
    }
    sagg[w][0][l] = g0a + g0b;
    sagg[w][1][l] = g1a + g1b;
    __syncthreads();

    if (w < 2) {
      const int irow = i_r0 + w;
      rag[w][l] = sagg[0][w][l] + sagg[1][w][l] + sagg[2][w][l] + sagg[3][w][l];
      xis[w][l] = xb[(size_t)irow * DD + l];
      float acc = 0.f;
      #pragma unroll 8
      for (int d = 0; d < 64; ++d) {
        acc = fmaf(rag[w][d], pwa[d * 64 + l], acc);
        acc = fmaf(xis[w][d], pwoa[d * 64 + l], acc);
      }
      acc += pwab[l] + pwob[l];
      float hb = (acc - mu[l]) * rsqrtf(var[l] + 1e-5f) * gam[l] + bet[l];
      const float SC = 1.0507009873554805f, AL = 1.6732632423543772f;
      float hv = hb > 0.f ? SC * hb : SC * AL * expm1f(hb);
      h[((size_t)(b * NN + irow)) * DD + l] = hv;

      float p = hv * poolw[l];
      #pragma unroll
      for (int off = 32; off; off >>= 1) p += __shfl_xor(p, off, 64);
      if (l == 0) s[b * NN + irow] = 1.f / (1.f + expf(-(p + poolb[0])));
    }
    __syncthreads();  // protect rag/xis/sagg before next iteration reuses LDS
  }
}

// ====== Kernel C: fused per-batch rank-select top-k + gather =================
__global__ __launch_bounds__(512) void k_sel(
    const float* __restrict__ s, const float* __restrict__ h,
    float* __restrict__ out) {
  __shared__ float svv[NN];
  __shared__ int inv[NKEEP];
  __shared__ float sval[NKEEP];
  const int b = blockIdx.x, t = threadIdx.x;
  svv[t] = s[b * NN + t];
  __syncthreads();

  const float my = svv[t];
  int r = 0;
  #pragma unroll 4
  for (int j0 = 0; j0 < NN; j0 += 4) {
    float4 v = *reinterpret_cast<const float4*>(&svv[j0]);
    r += (v.x > my) || (v.x == my && (j0 + 0) < t);
    r += (v.y > my) || (v.y == my && (j0 + 1) < t);
    r += (v.z > my) || (v.z == my && (j0 + 2) < t);
    r += (v.w > my) || (v.w == my && (j0 + 3) < t);
  }
  if (r < NKEEP) { inv[r] = t; sval[r] = my; }
  __syncthreads();

  #pragma unroll
  for (int pos = t; pos < NKEEP * 16; pos += 512) {
    const int kk = pos >> 4, d4 = (pos & 15) * 4;
    const int i = inv[kk];
    const float sc = sval[kk];
    float4 v = *reinterpret_cast<const float4*>(
        h + ((size_t)(b * NN + i)) * DD + d4);
    v.x *= sc; v.y *= sc; v.z *= sc; v.w *= sc;
    *reinterpret_cast<float4*>(out + ((size_t)(b * NKEEP + kk)) * DD + d4) = v;
  }
}

extern "C" void kernel_launch(void* const* d_in, const int* in_sizes, int n_in,
                              void* d_out, int out_size, void* d_ws, size_t ws_size,
                              hipStream_t stream) {
  const float* x     = (const float*)d_in[0];
  const float* apw   = (const float*)d_in[1];
  const float* apb   = (const float*)d_in[2];
  const float* aw    = (const float*)d_in[3];
  const float* pwa   = (const float*)d_in[4];
  const float* pwab  = (const float*)d_in[5];
  const float* pwoa  = (const float*)d_in[6];
  const float* pwob  = (const float*)d_in[7];
  const float* gam   = (const float*)d_in[8];
  const float* bet   = (const float*)d_in[9];
  const float* mu    = (const float*)d_in[10];
  const float* var   = (const float*)d_in[11];
  const float* poolw = (const float*)d_in[12];
  const float* poolb = (const float*)d_in[13];
  float* out = (float*)d_out;

  float* sT = (float*)d_ws;                     // 4 MB
  float* h  = sT + (size_t)BSZ * NN * NN;       // 512 KB
  float* s  = h + (size_t)BSZ * NN * DD;        // 8 KB

  k_score<<<512, 256, 0, stream>>>(x, apw, apb, aw, sT);
  k_soft<<<512, 256, 0, stream>>>(x, sT, pwa, pwab, pwoa, pwob,
                                  gam, bet, mu, var, poolw, poolb, h, s);
  k_sel<<<BSZ, 512, 0, stream>>>(s, h, out);
}